// Round 14
// baseline (310.531 us; speedup 1.0000x reference)
//
#include <hip/hip_runtime.h>

#define N_NODES 50000
#define N_EDGES 800000
#define N_GRAPHS 512
#define DIM 128
#define N_PAD 50048

#define BW_LOG 9
#define BWID 512                                  // nodes per bucket
#define NB ((N_NODES + BWID - 1) / BWID)          // 98
#define CHUNK 4096                                // edges per phase-A block
#define NCHUNK ((N_EDGES + CHUNK - 1) / CHUNK)    // 196

typedef unsigned int uint;
typedef unsigned short ushort;
typedef unsigned long long ull;
typedef __attribute__((ext_vector_type(8))) short bf16x8;
typedef __attribute__((ext_vector_type(4))) float f32x4;

// bf16 helpers (RNE pack, cheap unpack)
__device__ __forceinline__ ushort f2bf(float f) {
    uint u = __float_as_uint(f);
    return (ushort)((u + 0x7fffu + ((u >> 16) & 1u)) >> 16);
}
__device__ __forceinline__ float bf2f(ushort h) { return __uint_as_float((uint)h << 16); }
__device__ __forceinline__ float bflo(uint p) { return __uint_as_float(p << 16); }
__device__ __forceinline__ float bfhi(uint p) { return __uint_as_float(p & 0xffff0000u); }

// ---------------- CSR build: bucket-sorted ----------------

__global__ __launch_bounds__(256) void bhist_k(const int* __restrict__ dst,
                                               int* __restrict__ bcnt_pad, int e) {
    __shared__ int h[NB];
    int t = threadIdx.x;
    for (int i = t; i < NB; i += 256) h[i] = 0;
    __syncthreads();
    int base = blockIdx.x * CHUNK;
    for (int i = t; i < CHUNK; i += 256) {
        int idx = base + i;
        if (idx < e) atomicAdd(&h[dst[idx] >> BW_LOG], 1);
    }
    __syncthreads();
    for (int i = t; i < NB; i += 256)
        if (h[i]) atomicAdd(&bcnt_pad[i << 4], h[i]);
}

// parallel 98-wide exclusive scan (one 128-thread block)
__global__ void bscan_k(const int* __restrict__ bcnt_pad, int* __restrict__ bbase,
                        int* __restrict__ bcur_pad) {
    __shared__ int v[128];
    int t = threadIdx.x;
    int x = (t < NB) ? bcnt_pad[t << 4] : 0;
    v[t] = x;
    __syncthreads();
    for (int o = 1; o < 128; o <<= 1) {
        int val = v[t];
        int add = (t >= o) ? v[t - o] : 0;
        __syncthreads();
        v[t] = val + add;
        __syncthreads();
    }
    if (t < NB) {
        int excl = (t == 0) ? 0 : v[t - 1];
        bbase[t] = excl;
        bcur_pad[t << 4] = excl;
    }
    if (t == NB - 1) bbase[NB] = v[t];
}

// packed record: (src << 9) | (dst & 511)
__global__ __launch_bounds__(256) void bscat_k(const int* __restrict__ src,
                                               const int* __restrict__ dst,
                                               int* __restrict__ bcur_pad,
                                               uint* __restrict__ stage, int e) {
    __shared__ int h[NB];
    __shared__ int bb[NB];
    __shared__ int lc[NB];
    int t = threadIdx.x;
    for (int i = t; i < NB; i += 256) h[i] = 0;
    __syncthreads();
    int base = blockIdx.x * CHUNK;
    for (int i = t; i < CHUNK; i += 256) {
        int idx = base + i;
        if (idx < e) atomicAdd(&h[dst[idx] >> BW_LOG], 1);
    }
    __syncthreads();
    for (int i = t; i < NB; i += 256) {
        int c = h[i];
        bb[i] = c ? atomicAdd(&bcur_pad[i << 4], c) : 0;
        lc[i] = 0;
    }
    __syncthreads();
    for (int i = t; i < CHUNK; i += 256) {
        int idx = base + i;
        if (idx < e) {
            int d = dst[idx];
            int b = d >> BW_LOG;
            int r = atomicAdd(&lc[b], 1);
            stage[bb[b] + r] = ((uint)src[idx] << BW_LOG) | (uint)(d & (BWID - 1));
        }
    }
}

__global__ __launch_bounds__(256) void csr_k(const uint* __restrict__ stage,
                                             const int* __restrict__ bbase,
                                             int* __restrict__ row_ptr,
                                             float* __restrict__ dis,
                                             int* __restrict__ col) {
    __shared__ int hist[BWID];
    __shared__ int excl[BWID];
    __shared__ int ws[256];
    int b = blockIdx.x, t = threadIdx.x;
    int beg = bbase[b], end = bbase[b + 1];
    for (int i = t; i < BWID; i += 256) hist[i] = 0;
    __syncthreads();
    for (int i = beg + t; i < end; i += 256)
        atomicAdd(&hist[stage[i] & (BWID - 1)], 1);
    __syncthreads();
    int s = hist[2 * t] + hist[2 * t + 1];
    ws[t] = s;
    __syncthreads();
    for (int o = 1; o < 256; o <<= 1) {
        int v = ws[t];
        int add = (t >= o) ? ws[t - o] : 0;
        __syncthreads();
        ws[t] = v + add;
        __syncthreads();
    }
    int pre = (t == 0) ? 0 : ws[t - 1];
    excl[2 * t] = pre;
    excl[2 * t + 1] = pre + hist[2 * t];
    __syncthreads();
    int node0 = b * BWID;
    for (int i = t; i < BWID; i += 256) {
        int node = node0 + i;
        if (node < N_NODES) {
            row_ptr[node] = beg + excl[i];
            dis[node] = rsqrtf((float)(hist[i] + 1));   // +1 = self-loop
        } else if (node == N_NODES) {
            row_ptr[node] = beg + excl[i];
        }
    }
    __syncthreads();
    for (int i = t; i < BWID; i += 256) hist[i] = excl[i];
    __syncthreads();
    for (int i = beg + t; i < end; i += 256) {
        uint p = stage[i];
        int d9 = p & (BWID - 1);
        int r = atomicAdd(&hist[d9], 1);
        col[beg + r] = (int)(p >> BW_LOG);
    }
}

// ---------------- W conversion: split-precision, n-major, all 3 layers ----------------

__global__ void wconv_k(const float* __restrict__ Wa, const float* __restrict__ Wb,
                        const float* __restrict__ Wc, ushort* __restrict__ Whi,
                        ushort* __restrict__ Wlo) {
    int i = blockIdx.x * 256 + threadIdx.x;   // 3*16384
    int layer = i >> 14, r = i & 16383;
    const float* W = layer == 0 ? Wa : (layer == 1 ? Wb : Wc);
    int k = r >> 7, nn = r & 127;
    float w = W[r];
    ushort h = f2bf(w);
    size_t o = (size_t)layer * DIM * DIM + nn * 128 + k;
    Whi[o] = h;
    Wlo[o] = f2bf(w - bf2f(h));
}

// ---------------- MFMA GEMM, split-precision W (and A for fp32 input) ----------------

template <typename TIn>
__global__ __launch_bounds__(256) void gemm_mfma_k(const TIn* __restrict__ X,
                                                   const ushort* __restrict__ Whi,
                                                   const ushort* __restrict__ Wlo,
                                                   ushort* __restrict__ H, int n) {
    __shared__ __align__(16) ushort lds[128 * 136];   // 34 KB; re-staged per pass
    int t = threadIdx.x;

    auto stageW = [&](const ushort* Wsw) {
#pragma unroll
        for (int j = 0; j < 8; j++) {
            int idx8 = t + j * 256;              // 2048 octets
            int nn = idx8 >> 4;
            int k0 = (idx8 & 15) * 8;
            uint4 v = ((const uint4*)Wsw)[idx8];
            *(uint4*)&lds[nn * 136 + k0] = v;
        }
    };

    stageW(Whi);

    int w = t >> 6, l = t & 63;
    int quad = l >> 4, lr = l & 15;
    int arow = blockIdx.x * 64 + w * 16 + lr;
    int srow = arow < n ? arow : n - 1;          // clamp: no OOB read

    bf16x8 a[4], alo[4];
#pragma unroll
    for (int q = 0; q < 4; q++) {
        if constexpr (sizeof(TIn) == 4) {
            const float4* xp = (const float4*)(X + (size_t)srow * DIM + q * 32 + quad * 8);
            float4 v0 = xp[0], v1 = xp[1];
            float f[8] = {v0.x, v0.y, v0.z, v0.w, v1.x, v1.y, v1.z, v1.w};
            bf16x8 ah, al;
#pragma unroll
            for (int j = 0; j < 8; j++) {
                ushort h = f2bf(f[j]);
                ah[j] = (short)h;
                al[j] = (short)f2bf(f[j] - bf2f(h));
            }
            a[q] = ah;
            alo[q] = al;
        } else {
            a[q] = *(const bf16x8*)(X + (size_t)srow * DIM + q * 32 + quad * 8);
        }
    }

    f32x4 acc[8];
#pragma unroll
    for (int c = 0; c < 8; c++) acc[c] = (f32x4){0.f, 0.f, 0.f, 0.f};

    __syncthreads();
#pragma unroll
    for (int q = 0; q < 4; q++) {
#pragma unroll
        for (int c = 0; c < 8; c++) {
            bf16x8 b = *(const bf16x8*)&lds[(c * 16 + lr) * 136 + q * 32 + quad * 8];
            acc[c] = __builtin_amdgcn_mfma_f32_16x16x32_bf16(a[q], b, acc[c], 0, 0, 0);
            if constexpr (sizeof(TIn) == 4)
                acc[c] = __builtin_amdgcn_mfma_f32_16x16x32_bf16(alo[q], b, acc[c], 0, 0, 0);
        }
    }

    __syncthreads();
    stageW(Wlo);
    __syncthreads();
#pragma unroll
    for (int q = 0; q < 4; q++) {
#pragma unroll
        for (int c = 0; c < 8; c++) {
            bf16x8 b = *(const bf16x8*)&lds[(c * 16 + lr) * 136 + q * 32 + quad * 8];
            acc[c] = __builtin_amdgcn_mfma_f32_16x16x32_bf16(a[q], b, acc[c], 0, 0, 0);
        }
    }

    __syncthreads();
#pragma unroll
    for (int c = 0; c < 8; c++) {
#pragma unroll
        for (int r = 0; r < 4; r++) {
            int rl = w * 16 + quad * 4 + r;
            lds[rl * 136 + c * 16 + lr] = f2bf(acc[c][r]);
        }
    }
    __syncthreads();
#pragma unroll
    for (int j = 0; j < 4; j++) {
        int idx = t + j * 256;                   // 1024 slots = 64 rows x 16 uint4
        int rl = idx >> 4, sl = idx & 15;
        int grow = blockIdx.x * 64 + rl;
        if (grow < n) {
            uint4 v = *(const uint4*)&lds[rl * 136 + sl * 8];
            ((uint4*)(H + (size_t)grow * DIM))[sl] = v;
        }
    }
}

// ---------------- CSR aggregation: 16 lanes/node, uint4 gathers, 4-edge unroll --------

#define AGG_BODY                                                                 \
    const ushort* Hl = H + lane * 8;                                             \
    float dn = dis[node];                                                        \
    int beg = row_ptr[node], end = row_ptr[node + 1];                            \
    uint4 pw = *(const uint4*)(Hl + (size_t)node * DIM);                         \
    a0 = dn * bflo(pw.x); a1 = dn * bfhi(pw.x);                                  \
    a2 = dn * bflo(pw.y); a3 = dn * bfhi(pw.y);                                  \
    a4 = dn * bflo(pw.z); a5 = dn * bfhi(pw.z);                                  \
    a6 = dn * bflo(pw.w); a7 = dn * bfhi(pw.w);                                  \
    int e = beg;                                                                 \
    for (; e + 3 < end; e += 4) {                                                \
        int c0 = col[e], c1 = col[e + 1], c2 = col[e + 2], c3 = col[e + 3];      \
        float w0 = dis[c0], w1 = dis[c1], w2 = dis[c2], w3 = dis[c3];            \
        uint4 p0 = *(const uint4*)(Hl + (size_t)c0 * DIM);                       \
        uint4 p1 = *(const uint4*)(Hl + (size_t)c1 * DIM);                       \
        uint4 p2 = *(const uint4*)(Hl + (size_t)c2 * DIM);                       \
        uint4 p3 = *(const uint4*)(Hl + (size_t)c3 * DIM);                       \
        a0 += w0 * bflo(p0.x) + w1 * bflo(p1.x) + w2 * bflo(p2.x) + w3 * bflo(p3.x); \
        a1 += w0 * bfhi(p0.x) + w1 * bfhi(p1.x) + w2 * bfhi(p2.x) + w3 * bfhi(p3.x); \
        a2 += w0 * bflo(p0.y) + w1 * bflo(p1.y) + w2 * bflo(p2.y) + w3 * bflo(p3.y); \
        a3 += w0 * bfhi(p0.y) + w1 * bfhi(p1.y) + w2 * bfhi(p2.y) + w3 * bfhi(p3.y); \
        a4 += w0 * bflo(p0.z) + w1 * bflo(p1.z) + w2 * bflo(p2.z) + w3 * bflo(p3.z); \
        a5 += w0 * bfhi(p0.z) + w1 * bfhi(p1.z) + w2 * bfhi(p2.z) + w3 * bfhi(p3.z); \
        a6 += w0 * bflo(p0.w) + w1 * bflo(p1.w) + w2 * bflo(p2.w) + w3 * bflo(p3.w); \
        a7 += w0 * bfhi(p0.w) + w1 * bfhi(p1.w) + w2 * bfhi(p2.w) + w3 * bfhi(p3.w); \
    }                                                                            \
    for (; e < end; e++) {                                                       \
        int c = col[e];                                                          \
        float w = dis[c];                                                        \
        uint4 p = *(const uint4*)(Hl + (size_t)c * DIM);                         \
        a0 += w * bflo(p.x); a1 += w * bfhi(p.x);                                \
        a2 += w * bflo(p.y); a3 += w * bfhi(p.y);                                \
        a4 += w * bflo(p.z); a5 += w * bfhi(p.z);                                \
        a6 += w * bflo(p.w); a7 += w * bfhi(p.w);                                \
    }                                                                            \
    a0 = fmaxf(a0 * dn + bias[d0], 0.f);                                         \
    a1 = fmaxf(a1 * dn + bias[d0 + 1], 0.f);                                     \
    a2 = fmaxf(a2 * dn + bias[d0 + 2], 0.f);                                     \
    a3 = fmaxf(a3 * dn + bias[d0 + 3], 0.f);                                     \
    a4 = fmaxf(a4 * dn + bias[d0 + 4], 0.f);                                     \
    a5 = fmaxf(a5 * dn + bias[d0 + 5], 0.f);                                     \
    a6 = fmaxf(a6 * dn + bias[d0 + 6], 0.f);                                     \
    a7 = fmaxf(a7 * dn + bias[d0 + 7], 0.f);

__global__ __launch_bounds__(256) void agg_k(const ushort* __restrict__ H,
                                             const int* __restrict__ row_ptr,
                                             const int* __restrict__ col,
                                             const float* __restrict__ dis,
                                             const float* __restrict__ bias,
                                             ushort* __restrict__ Out, int n) {
    int node = blockIdx.x * 16 + (threadIdx.x >> 4);
    int lane = threadIdx.x & 15;
    if (node >= n) return;
    int d0 = lane * 8;
    float a0, a1, a2, a3, a4, a5, a6, a7;
    AGG_BODY
    uint4 o;
    o.x = (uint)f2bf(a0) | ((uint)f2bf(a1) << 16);
    o.y = (uint)f2bf(a2) | ((uint)f2bf(a3) << 16);
    o.z = (uint)f2bf(a4) | ((uint)f2bf(a5) << 16);
    o.w = (uint)f2bf(a6) | ((uint)f2bf(a7) << 16);
    *(uint4*)(Out + (size_t)node * DIM + d0) = o;
}

// layer-3 agg fused with global_add_pool — BARRIER-FREE per-wave reduction.
// Wave = 4 node-groups. If all 4 nodes share one graph (common: ~98 nodes/graph),
// butterfly-reduce across groups (shfl_xor 16/32) -> 128 atomics/wave.
// Mixed/tail waves: per-lane atomics (rare). No __syncthreads.
__global__ __launch_bounds__(256) void agg_pool_k(const ushort* __restrict__ H,
                                                  const int* __restrict__ row_ptr,
                                                  const int* __restrict__ col,
                                                  const float* __restrict__ dis,
                                                  const float* __restrict__ bias,
                                                  const int* __restrict__ batch,
                                                  float* __restrict__ Out, int n) {
    int t = threadIdx.x;
    int node = blockIdx.x * 16 + (t >> 4);
    int lane = t & 15;
    int d0 = lane * 8;
    float a0 = 0.f, a1 = 0.f, a2 = 0.f, a3 = 0.f, a4 = 0.f, a5 = 0.f, a6 = 0.f, a7 = 0.f;
    int g = -1;
    if (node < n) {
        AGG_BODY
        g = batch[node];
    }
    int lid = t & 63;
    int g0 = __shfl(g, 0, 64);
    ull same = __ballot(g == g0);
    if (same == ~0ULL && g0 >= 0) {
        // uniform wave: reduce 4 groups -> lanes 0..15, 8 atomics each
        a0 += __shfl_xor(a0, 16, 64); a0 += __shfl_xor(a0, 32, 64);
        a1 += __shfl_xor(a1, 16, 64); a1 += __shfl_xor(a1, 32, 64);
        a2 += __shfl_xor(a2, 16, 64); a2 += __shfl_xor(a2, 32, 64);
        a3 += __shfl_xor(a3, 16, 64); a3 += __shfl_xor(a3, 32, 64);
        a4 += __shfl_xor(a4, 16, 64); a4 += __shfl_xor(a4, 32, 64);
        a5 += __shfl_xor(a5, 16, 64); a5 += __shfl_xor(a5, 32, 64);
        a6 += __shfl_xor(a6, 16, 64); a6 += __shfl_xor(a6, 32, 64);
        a7 += __shfl_xor(a7, 16, 64); a7 += __shfl_xor(a7, 32, 64);
        if (lid < 16) {
            float* o = Out + (size_t)g0 * DIM + d0;
            atomicAdd(o + 0, a0);
            atomicAdd(o + 1, a1);
            atomicAdd(o + 2, a2);
            atomicAdd(o + 3, a3);
            atomicAdd(o + 4, a4);
            atomicAdd(o + 5, a5);
            atomicAdd(o + 6, a6);
            atomicAdd(o + 7, a7);
        }
    } else if (g >= 0) {
        float* o = Out + (size_t)g * DIM + d0;
        atomicAdd(o + 0, a0);
        atomicAdd(o + 1, a1);
        atomicAdd(o + 2, a2);
        atomicAdd(o + 3, a3);
        atomicAdd(o + 4, a4);
        atomicAdd(o + 5, a5);
        atomicAdd(o + 6, a6);
        atomicAdd(o + 7, a7);
    }
}

// ---------------- launch ----------------

extern "C" void kernel_launch(void* const* d_in, const int* in_sizes, int n_in,
                              void* d_out, int out_size, void* d_ws, size_t ws_size,
                              hipStream_t stream) {
    const float* x  = (const float*)d_in[0];
    const float* W1 = (const float*)d_in[1];
    const float* b1 = (const float*)d_in[2];
    const float* W2 = (const float*)d_in[3];
    const float* b2 = (const float*)d_in[4];
    const float* W3 = (const float*)d_in[5];
    const float* b3 = (const float*)d_in[6];
    const int*   ei = (const int*)d_in[7];
    const int*   bv = (const int*)d_in[8];
    float* out = (float*)d_out;

    const int N = N_NODES, E = N_EDGES;

    char* p = (char*)d_ws;
    auto alloc = [&](size_t bytes) -> void* {
        void* r = (void*)p;
        p += (bytes + 255) & ~(size_t)255;
        return r;
    };
    int*    bcnt_pad = (int*)alloc((size_t)NB * 16 * 4);
    int*    bcur_pad = (int*)alloc((size_t)NB * 16 * 4);
    int*    bbase    = (int*)alloc((size_t)(NB + 1) * 4);
    int*    row_ptr  = (int*)alloc((size_t)(N + 1) * 4);
    float*  dis      = (float*)alloc((size_t)N * 4);
    uint*   stage    = (uint*)alloc((size_t)E * 4);
    int*    col      = (int*)alloc((size_t)E * 4);
    ushort* B1       = (ushort*)alloc((size_t)N_PAD * DIM * 2);
    ushort* B2       = (ushort*)alloc((size_t)N_PAD * DIM * 2);

    // W buffers overlaid on stage (dead after csr_k; wconv runs after it in-stream)
    ushort* Whi = (ushort*)stage;                        // 3 * 16384
    ushort* Wlo = Whi + (size_t)3 * DIM * DIM;

    const int* src = ei;
    const int* dst = ei + E;

    hipMemsetAsync(d_out, 0, (size_t)N_GRAPHS * DIM * sizeof(float), stream);
    hipMemsetAsync(bcnt_pad, 0, (size_t)NB * 16 * 4, stream);

    bhist_k<<<NCHUNK, 256, 0, stream>>>(dst, bcnt_pad, E);
    bscan_k<<<1, 128, 0, stream>>>(bcnt_pad, bbase, bcur_pad);
    bscat_k<<<NCHUNK, 256, 0, stream>>>(src, dst, bcur_pad, stage, E);
    csr_k<<<NB, 256, 0, stream>>>(stage, bbase, row_ptr, dis, col);

    wconv_k<<<192, 256, 0, stream>>>(W1, W2, W3, Whi, Wlo);

    int gemm_grid = N_PAD / 64;          // 782
    int agg_grid  = (N + 15) / 16;

    gemm_mfma_k<float><<<gemm_grid, 256, 0, stream>>>(x, Whi, Wlo, B1, N);
    agg_k<<<agg_grid, 256, 0, stream>>>(B1, row_ptr, col, dis, b1, B2, N);

    gemm_mfma_k<ushort><<<gemm_grid, 256, 0, stream>>>(B2, Whi + (size_t)DIM * DIM,
                                                       Wlo + (size_t)DIM * DIM, B1, N);
    agg_k<<<agg_grid, 256, 0, stream>>>(B1, row_ptr, col, dis, b2, B2, N);

    gemm_mfma_k<ushort><<<gemm_grid, 256, 0, stream>>>(B2, Whi + (size_t)2 * DIM * DIM,
                                                       Wlo + (size_t)2 * DIM * DIM, B1, N);
    agg_pool_k<<<agg_grid, 256, 0, stream>>>(B1, row_ptr, col, dis, b3, bv, out, N);
}

// Round 15
// 287.192 us; speedup vs baseline: 1.0813x; 1.0813x over previous
//
#include <hip/hip_runtime.h>

#define N_NODES 50000
#define N_EDGES 800000
#define N_GRAPHS 512
#define DIM 128
#define N_PAD 50048

#define BW_LOG 9
#define BWID 512                                  // nodes per bucket
#define NB ((N_NODES + BWID - 1) / BWID)          // 98
#define CHUNK 4096                                // edges per phase-A block
#define NCHUNK ((N_EDGES + CHUNK - 1) / CHUNK)    // 196

typedef unsigned int uint;
typedef unsigned short ushort;
typedef __attribute__((ext_vector_type(8))) short bf16x8;
typedef __attribute__((ext_vector_type(4))) float f32x4;

// bf16 helpers (RNE pack, cheap unpack)
__device__ __forceinline__ ushort f2bf(float f) {
    uint u = __float_as_uint(f);
    return (ushort)((u + 0x7fffu + ((u >> 16) & 1u)) >> 16);
}
__device__ __forceinline__ float bf2f(ushort h) { return __uint_as_float((uint)h << 16); }
__device__ __forceinline__ float bflo(uint p) { return __uint_as_float(p << 16); }
__device__ __forceinline__ float bfhi(uint p) { return __uint_as_float(p & 0xffff0000u); }

// ---------------- CSR build: bucket-sorted ----------------

__global__ __launch_bounds__(256) void bhist_k(const int* __restrict__ dst,
                                               int* __restrict__ bcnt_pad, int e) {
    __shared__ int h[NB];
    int t = threadIdx.x;
    for (int i = t; i < NB; i += 256) h[i] = 0;
    __syncthreads();
    int base = blockIdx.x * CHUNK;
    for (int i = t; i < CHUNK; i += 256) {
        int idx = base + i;
        if (idx < e) atomicAdd(&h[dst[idx] >> BW_LOG], 1);
    }
    __syncthreads();
    for (int i = t; i < NB; i += 256)
        if (h[i]) atomicAdd(&bcnt_pad[i << 4], h[i]);
}

// parallel 98-wide exclusive scan (one 128-thread block)
__global__ void bscan_k(const int* __restrict__ bcnt_pad, int* __restrict__ bbase,
                        int* __restrict__ bcur_pad) {
    __shared__ int v[128];
    int t = threadIdx.x;
    int x = (t < NB) ? bcnt_pad[t << 4] : 0;
    v[t] = x;
    __syncthreads();
    for (int o = 1; o < 128; o <<= 1) {
        int val = v[t];
        int add = (t >= o) ? v[t - o] : 0;
        __syncthreads();
        v[t] = val + add;
        __syncthreads();
    }
    if (t < NB) {
        int excl = (t == 0) ? 0 : v[t - 1];
        bbase[t] = excl;
        bcur_pad[t << 4] = excl;
    }
    if (t == NB - 1) bbase[NB] = v[t];
}

// packed record: (src << 9) | (dst & 511)
__global__ __launch_bounds__(256) void bscat_k(const int* __restrict__ src,
                                               const int* __restrict__ dst,
                                               int* __restrict__ bcur_pad,
                                               uint* __restrict__ stage, int e) {
    __shared__ int h[NB];
    __shared__ int bb[NB];
    __shared__ int lc[NB];
    int t = threadIdx.x;
    for (int i = t; i < NB; i += 256) h[i] = 0;
    __syncthreads();
    int base = blockIdx.x * CHUNK;
    for (int i = t; i < CHUNK; i += 256) {
        int idx = base + i;
        if (idx < e) atomicAdd(&h[dst[idx] >> BW_LOG], 1);
    }
    __syncthreads();
    for (int i = t; i < NB; i += 256) {
        int c = h[i];
        bb[i] = c ? atomicAdd(&bcur_pad[i << 4], c) : 0;
        lc[i] = 0;
    }
    __syncthreads();
    for (int i = t; i < CHUNK; i += 256) {
        int idx = base + i;
        if (idx < e) {
            int d = dst[idx];
            int b = d >> BW_LOG;
            int r = atomicAdd(&lc[b], 1);
            stage[bb[b] + r] = ((uint)src[idx] << BW_LOG) | (uint)(d & (BWID - 1));
        }
    }
}

__global__ __launch_bounds__(256) void csr_k(const uint* __restrict__ stage,
                                             const int* __restrict__ bbase,
                                             int* __restrict__ row_ptr,
                                             float* __restrict__ dis,
                                             int* __restrict__ col) {
    __shared__ int hist[BWID];
    __shared__ int excl[BWID];
    __shared__ int ws[256];
    int b = blockIdx.x, t = threadIdx.x;
    int beg = bbase[b], end = bbase[b + 1];
    for (int i = t; i < BWID; i += 256) hist[i] = 0;
    __syncthreads();
    for (int i = beg + t; i < end; i += 256)
        atomicAdd(&hist[stage[i] & (BWID - 1)], 1);
    __syncthreads();
    int s = hist[2 * t] + hist[2 * t + 1];
    ws[t] = s;
    __syncthreads();
    for (int o = 1; o < 256; o <<= 1) {
        int v = ws[t];
        int add = (t >= o) ? ws[t - o] : 0;
        __syncthreads();
        ws[t] = v + add;
        __syncthreads();
    }
    int pre = (t == 0) ? 0 : ws[t - 1];
    excl[2 * t] = pre;
    excl[2 * t + 1] = pre + hist[2 * t];
    __syncthreads();
    int node0 = b * BWID;
    for (int i = t; i < BWID; i += 256) {
        int node = node0 + i;
        if (node < N_NODES) {
            row_ptr[node] = beg + excl[i];
            dis[node] = rsqrtf((float)(hist[i] + 1));   // +1 = self-loop
        } else if (node == N_NODES) {
            row_ptr[node] = beg + excl[i];
        }
    }
    __syncthreads();
    for (int i = t; i < BWID; i += 256) hist[i] = excl[i];
    __syncthreads();
    for (int i = beg + t; i < end; i += 256) {
        uint p = stage[i];
        int d9 = p & (BWID - 1);
        int r = atomicAdd(&hist[d9], 1);
        col[beg + r] = (int)(p >> BW_LOG);
    }
}

// ---------------- W conversion: split-precision, n-major, all 3 layers ----------------

__global__ void wconv_k(const float* __restrict__ Wa, const float* __restrict__ Wb,
                        const float* __restrict__ Wc, ushort* __restrict__ Whi,
                        ushort* __restrict__ Wlo) {
    int i = blockIdx.x * 256 + threadIdx.x;   // 3*16384
    int layer = i >> 14, r = i & 16383;
    const float* W = layer == 0 ? Wa : (layer == 1 ? Wb : Wc);
    int k = r >> 7, nn = r & 127;
    float w = W[r];
    ushort h = f2bf(w);
    size_t o = (size_t)layer * DIM * DIM + nn * 128 + k;
    Whi[o] = h;
    Wlo[o] = f2bf(w - bf2f(h));
}

// ---------------- MFMA GEMM, split-precision W (and A for fp32 input) ----------------

template <typename TIn>
__global__ __launch_bounds__(256) void gemm_mfma_k(const TIn* __restrict__ X,
                                                   const ushort* __restrict__ Whi,
                                                   const ushort* __restrict__ Wlo,
                                                   ushort* __restrict__ H, int n) {
    __shared__ __align__(16) ushort lds[128 * 136];   // 34 KB; re-staged per pass
    int t = threadIdx.x;

    auto stageW = [&](const ushort* Wsw) {
#pragma unroll
        for (int j = 0; j < 8; j++) {
            int idx8 = t + j * 256;              // 2048 octets
            int nn = idx8 >> 4;
            int k0 = (idx8 & 15) * 8;
            uint4 v = ((const uint4*)Wsw)[idx8];
            *(uint4*)&lds[nn * 136 + k0] = v;
        }
    };

    stageW(Whi);

    int w = t >> 6, l = t & 63;
    int quad = l >> 4, lr = l & 15;
    int arow = blockIdx.x * 64 + w * 16 + lr;
    int srow = arow < n ? arow : n - 1;          // clamp: no OOB read

    bf16x8 a[4], alo[4];
#pragma unroll
    for (int q = 0; q < 4; q++) {
        if constexpr (sizeof(TIn) == 4) {
            const float4* xp = (const float4*)(X + (size_t)srow * DIM + q * 32 + quad * 8);
            float4 v0 = xp[0], v1 = xp[1];
            float f[8] = {v0.x, v0.y, v0.z, v0.w, v1.x, v1.y, v1.z, v1.w};
            bf16x8 ah, al;
#pragma unroll
            for (int j = 0; j < 8; j++) {
                ushort h = f2bf(f[j]);
                ah[j] = (short)h;
                al[j] = (short)f2bf(f[j] - bf2f(h));
            }
            a[q] = ah;
            alo[q] = al;
        } else {
            a[q] = *(const bf16x8*)(X + (size_t)srow * DIM + q * 32 + quad * 8);
        }
    }

    f32x4 acc[8];
#pragma unroll
    for (int c = 0; c < 8; c++) acc[c] = (f32x4){0.f, 0.f, 0.f, 0.f};

    __syncthreads();
#pragma unroll
    for (int q = 0; q < 4; q++) {
#pragma unroll
        for (int c = 0; c < 8; c++) {
            bf16x8 b = *(const bf16x8*)&lds[(c * 16 + lr) * 136 + q * 32 + quad * 8];
            acc[c] = __builtin_amdgcn_mfma_f32_16x16x32_bf16(a[q], b, acc[c], 0, 0, 0);
            if constexpr (sizeof(TIn) == 4)
                acc[c] = __builtin_amdgcn_mfma_f32_16x16x32_bf16(alo[q], b, acc[c], 0, 0, 0);
        }
    }

    __syncthreads();
    stageW(Wlo);
    __syncthreads();
#pragma unroll
    for (int q = 0; q < 4; q++) {
#pragma unroll
        for (int c = 0; c < 8; c++) {
            bf16x8 b = *(const bf16x8*)&lds[(c * 16 + lr) * 136 + q * 32 + quad * 8];
            acc[c] = __builtin_amdgcn_mfma_f32_16x16x32_bf16(a[q], b, acc[c], 0, 0, 0);
        }
    }

    __syncthreads();
#pragma unroll
    for (int c = 0; c < 8; c++) {
#pragma unroll
        for (int r = 0; r < 4; r++) {
            int rl = w * 16 + quad * 4 + r;
            lds[rl * 136 + c * 16 + lr] = f2bf(acc[c][r]);
        }
    }
    __syncthreads();
#pragma unroll
    for (int j = 0; j < 4; j++) {
        int idx = t + j * 256;                   // 1024 slots = 64 rows x 16 uint4
        int rl = idx >> 4, sl = idx & 15;
        int grow = blockIdx.x * 64 + rl;
        if (grow < n) {
            uint4 v = *(const uint4*)&lds[rl * 136 + sl * 8];
            ((uint4*)(H + (size_t)grow * DIM))[sl] = v;
        }
    }
}

// ---------------- CSR aggregation: 16 lanes/node, uint4 gathers, 4-edge unroll --------

#define AGG_BODY                                                                 \
    const ushort* Hl = H + lane * 8;                                             \
    float dn = dis[node];                                                        \
    int beg = row_ptr[node], end = row_ptr[node + 1];                            \
    uint4 pw = *(const uint4*)(Hl + (size_t)node * DIM);                         \
    a0 = dn * bflo(pw.x); a1 = dn * bfhi(pw.x);                                  \
    a2 = dn * bflo(pw.y); a3 = dn * bfhi(pw.y);                                  \
    a4 = dn * bflo(pw.z); a5 = dn * bfhi(pw.z);                                  \
    a6 = dn * bflo(pw.w); a7 = dn * bfhi(pw.w);                                  \
    int e = beg;                                                                 \
    for (; e + 3 < end; e += 4) {                                                \
        int c0 = col[e], c1 = col[e + 1], c2 = col[e + 2], c3 = col[e + 3];      \
        float w0 = dis[c0], w1 = dis[c1], w2 = dis[c2], w3 = dis[c3];            \
        uint4 p0 = *(const uint4*)(Hl + (size_t)c0 * DIM);                       \
        uint4 p1 = *(const uint4*)(Hl + (size_t)c1 * DIM);                       \
        uint4 p2 = *(const uint4*)(Hl + (size_t)c2 * DIM);                       \
        uint4 p3 = *(const uint4*)(Hl + (size_t)c3 * DIM);                       \
        a0 += w0 * bflo(p0.x) + w1 * bflo(p1.x) + w2 * bflo(p2.x) + w3 * bflo(p3.x); \
        a1 += w0 * bfhi(p0.x) + w1 * bfhi(p1.x) + w2 * bfhi(p2.x) + w3 * bfhi(p3.x); \
        a2 += w0 * bflo(p0.y) + w1 * bflo(p1.y) + w2 * bflo(p2.y) + w3 * bflo(p3.y); \
        a3 += w0 * bfhi(p0.y) + w1 * bfhi(p1.y) + w2 * bfhi(p2.y) + w3 * bfhi(p3.y); \
        a4 += w0 * bflo(p0.z) + w1 * bflo(p1.z) + w2 * bflo(p2.z) + w3 * bflo(p3.z); \
        a5 += w0 * bfhi(p0.z) + w1 * bfhi(p1.z) + w2 * bfhi(p2.z) + w3 * bfhi(p3.z); \
        a6 += w0 * bflo(p0.w) + w1 * bflo(p1.w) + w2 * bflo(p2.w) + w3 * bflo(p3.w); \
        a7 += w0 * bfhi(p0.w) + w1 * bfhi(p1.w) + w2 * bfhi(p2.w) + w3 * bfhi(p3.w); \
    }                                                                            \
    for (; e < end; e++) {                                                       \
        int c = col[e];                                                          \
        float w = dis[c];                                                        \
        uint4 p = *(const uint4*)(Hl + (size_t)c * DIM);                         \
        a0 += w * bflo(p.x); a1 += w * bfhi(p.x);                                \
        a2 += w * bflo(p.y); a3 += w * bfhi(p.y);                                \
        a4 += w * bflo(p.z); a5 += w * bfhi(p.z);                                \
        a6 += w * bflo(p.w); a7 += w * bfhi(p.w);                                \
    }                                                                            \
    a0 = fmaxf(a0 * dn + bias[d0], 0.f);                                         \
    a1 = fmaxf(a1 * dn + bias[d0 + 1], 0.f);                                     \
    a2 = fmaxf(a2 * dn + bias[d0 + 2], 0.f);                                     \
    a3 = fmaxf(a3 * dn + bias[d0 + 3], 0.f);                                     \
    a4 = fmaxf(a4 * dn + bias[d0 + 4], 0.f);                                     \
    a5 = fmaxf(a5 * dn + bias[d0 + 5], 0.f);                                     \
    a6 = fmaxf(a6 * dn + bias[d0 + 6], 0.f);                                     \
    a7 = fmaxf(a7 * dn + bias[d0 + 7], 0.f);

__global__ __launch_bounds__(256) void agg_k(const ushort* __restrict__ H,
                                             const int* __restrict__ row_ptr,
                                             const int* __restrict__ col,
                                             const float* __restrict__ dis,
                                             const float* __restrict__ bias,
                                             ushort* __restrict__ Out, int n) {
    int node = blockIdx.x * 16 + (threadIdx.x >> 4);
    int lane = threadIdx.x & 15;
    if (node >= n) return;
    int d0 = lane * 8;
    float a0, a1, a2, a3, a4, a5, a6, a7;
    AGG_BODY
    uint4 o;
    o.x = (uint)f2bf(a0) | ((uint)f2bf(a1) << 16);
    o.y = (uint)f2bf(a2) | ((uint)f2bf(a3) << 16);
    o.z = (uint)f2bf(a4) | ((uint)f2bf(a5) << 16);
    o.w = (uint)f2bf(a6) | ((uint)f2bf(a7) << 16);
    *(uint4*)(Out + (size_t)node * DIM + d0) = o;
}

// layer-3 agg fused with global_add_pool: LDS run-reduction over sorted batch ids,
// one global atomic per (run x feature). Final h never rounded to bf16.
// (Round-14 lesson: per-wave GLOBAL atomic fan-out explodes write traffic —
//  keep the block-level LDS funnel.)
__global__ __launch_bounds__(256) void agg_pool_k(const ushort* __restrict__ H,
                                                  const int* __restrict__ row_ptr,
                                                  const int* __restrict__ col,
                                                  const float* __restrict__ dis,
                                                  const float* __restrict__ bias,
                                                  const int* __restrict__ batch,
                                                  float* __restrict__ Out, int n) {
    __shared__ float acc[DIM];
    int t = threadIdx.x;
    int node = blockIdx.x * 16 + (t >> 4);
    int lane = t & 15;
    int d0 = lane * 8;
    float a0 = 0.f, a1 = 0.f, a2 = 0.f, a3 = 0.f, a4 = 0.f, a5 = 0.f, a6 = 0.f, a7 = 0.f;
    int g = -1;
    if (node < n) {
        AGG_BODY
        g = batch[node];
    }
    int first = blockIdx.x * 16;                       // always < n (grid = ceil(n/16))
    int last = first + 15 < n ? first + 15 : n - 1;
    int g0 = batch[first], g1 = batch[last];
    for (int gr = g0; gr <= g1; gr++) {
        if (t < DIM) acc[t] = 0.f;
        __syncthreads();
        if (g == gr) {
            atomicAdd(&acc[d0], a0);
            atomicAdd(&acc[d0 + 1], a1);
            atomicAdd(&acc[d0 + 2], a2);
            atomicAdd(&acc[d0 + 3], a3);
            atomicAdd(&acc[d0 + 4], a4);
            atomicAdd(&acc[d0 + 5], a5);
            atomicAdd(&acc[d0 + 6], a6);
            atomicAdd(&acc[d0 + 7], a7);
        }
        __syncthreads();
        if (t < DIM) atomicAdd(&Out[gr * DIM + t], acc[t]);
        __syncthreads();
    }
}

// ---------------- launch ----------------

extern "C" void kernel_launch(void* const* d_in, const int* in_sizes, int n_in,
                              void* d_out, int out_size, void* d_ws, size_t ws_size,
                              hipStream_t stream) {
    const float* x  = (const float*)d_in[0];
    const float* W1 = (const float*)d_in[1];
    const float* b1 = (const float*)d_in[2];
    const float* W2 = (const float*)d_in[3];
    const float* b2 = (const float*)d_in[4];
    const float* W3 = (const float*)d_in[5];
    const float* b3 = (const float*)d_in[6];
    const int*   ei = (const int*)d_in[7];
    const int*   bv = (const int*)d_in[8];
    float* out = (float*)d_out;

    const int N = N_NODES, E = N_EDGES;

    char* p = (char*)d_ws;
    auto alloc = [&](size_t bytes) -> void* {
        void* r = (void*)p;
        p += (bytes + 255) & ~(size_t)255;
        return r;
    };
    int*    bcnt_pad = (int*)alloc((size_t)NB * 16 * 4);
    int*    bcur_pad = (int*)alloc((size_t)NB * 16 * 4);
    int*    bbase    = (int*)alloc((size_t)(NB + 1) * 4);
    int*    row_ptr  = (int*)alloc((size_t)(N + 1) * 4);
    float*  dis      = (float*)alloc((size_t)N * 4);
    uint*   stage    = (uint*)alloc((size_t)E * 4);
    int*    col      = (int*)alloc((size_t)E * 4);
    ushort* B1       = (ushort*)alloc((size_t)N_PAD * DIM * 2);
    ushort* B2       = (ushort*)alloc((size_t)N_PAD * DIM * 2);

    // W buffers overlaid on stage (dead after csr_k; wconv runs after it in-stream)
    ushort* Whi = (ushort*)stage;                        // 3 * 16384
    ushort* Wlo = Whi + (size_t)3 * DIM * DIM;

    const int* src = ei;
    const int* dst = ei + E;

    hipMemsetAsync(d_out, 0, (size_t)N_GRAPHS * DIM * sizeof(float), stream);
    hipMemsetAsync(bcnt_pad, 0, (size_t)NB * 16 * 4, stream);

    bhist_k<<<NCHUNK, 256, 0, stream>>>(dst, bcnt_pad, E);
    bscan_k<<<1, 128, 0, stream>>>(bcnt_pad, bbase, bcur_pad);
    bscat_k<<<NCHUNK, 256, 0, stream>>>(src, dst, bcur_pad, stage, E);
    csr_k<<<NB, 256, 0, stream>>>(stage, bbase, row_ptr, dis, col);

    wconv_k<<<192, 256, 0, stream>>>(W1, W2, W3, Whi, Wlo);

    int gemm_grid = N_PAD / 64;          // 782
    int agg_grid  = (N + 15) / 16;

    gemm_mfma_k<float><<<gemm_grid, 256, 0, stream>>>(x, Whi, Wlo, B1, N);
    agg_k<<<agg_grid, 256, 0, stream>>>(B1, row_ptr, col, dis, b1, B2, N);

    gemm_mfma_k<ushort><<<gemm_grid, 256, 0, stream>>>(B2, Whi + (size_t)DIM * DIM,
                                                       Wlo + (size_t)DIM * DIM, B1, N);
    agg_k<<<agg_grid, 256, 0, stream>>>(B1, row_ptr, col, dis, b2, B2, N);

    gemm_mfma_k<ushort><<<gemm_grid, 256, 0, stream>>>(B2, Whi + (size_t)2 * DIM * DIM,
                                                       Wlo + (size_t)2 * DIM * DIM, B1, N);
    agg_pool_k<<<agg_grid, 256, 0, stream>>>(B1, row_ptr, col, dis, b3, bv, out, N);
}